// Round 2
// baseline (238.577 us; speedup 1.0000x reference)
//
#include <hip/hip_runtime.h>

#define BB 4
#define NN 10000
#define EE 200000
#define DD 32

__device__ __forceinline__ float fast_tanh(float v) {
    float a = fabsf(v);
    float e = __expf(2.0f * a);            // e^{2|v|}; overflows to +inf for big a -> r = 1
    float r = 1.0f - 2.0f / (e + 1.0f);
    return copysignf(r, v);
}

// One wave (64 lanes) per edge; no cross-lane ops.
// lane l: d = l&31 (output column), h = l>>5; computes batches {h, h+2}.
// x rows are wave-uniform (scalar loads); weight/bias streamed nontemporally.
__global__ __launch_bounds__(256) void edge_kernel(
    const float* __restrict__ x,        // (B,N,D)
    const int*   __restrict__ eidx,     // (2,E)
    const float* __restrict__ weight,   // (E,D,D)
    const float* __restrict__ bias,     // (E,D)
    float* __restrict__ sums,           // (B,N,D) accum
    float* __restrict__ cnt)            // (N)
{
    int wid = __builtin_amdgcn_readfirstlane((int)(threadIdx.x >> 6)); // wave id in block, uniform
    int e = blockIdx.x * 4 + wid;
    if (e >= EE) return;
    int lane = threadIdx.x & 63;
    int d = lane & 31;
    bool hi = (lane >> 5) != 0;   // h = hi?1:0

    int src = eidx[e];            // uniform -> scalar load
    int dst = eidx[EE + e];

    const float* __restrict__ W  = weight + (size_t)e * (DD * DD);
    const float* __restrict__ x0 = x + (size_t)src * DD;              // b=0
    const float* __restrict__ x1 = x0 + (size_t)NN * DD;              // b=1
    const float* __restrict__ x2 = x1 + (size_t)NN * DD;              // b=2
    const float* __restrict__ x3 = x2 + (size_t)NN * DD;              // b=3

    float acc0 = 0.f, acc1 = 0.f;
#pragma unroll
    for (int i = 0; i < DD; ++i) {
        float w  = __builtin_nontemporal_load(&W[i * DD + d]);  // coalesced 128B row
        float xa = hi ? x1[i] : x0[i];   // x[h,   src, i] (uniform scalars, VALU select)
        float xb = hi ? x3[i] : x2[i];   // x[h+2, src, i]
        acc0 = fmaf(xa, w, acc0);
        acc1 = fmaf(xb, w, acc1);
    }
    float bv = __builtin_nontemporal_load(&bias[(size_t)e * DD + d]);
    float o0 = fast_tanh(acc0 + bv);
    float o1 = fast_tanh(acc1 + bv);

    size_t nd = (size_t)NN * DD;
    float* s0 = &sums[(hi ? nd : 0) + (size_t)dst * DD + d];          // batch h
    atomicAdd(s0, o0);
    atomicAdd(s0 + 2 * nd, o1);                                       // batch h+2
    if (lane == 0) atomicAdd(&cnt[dst], 1.0f);
}

// One wave per node: agg = sums/max(cnt,1); state; batch-norm over (B,D)=128 vals.
__global__ __launch_bounds__(256) void node_kernel(
    const float* __restrict__ sums,     // (B,N,D)
    const float* __restrict__ cnt,      // (N)
    const float* __restrict__ state_w,  // (D,1)
    const float* __restrict__ state_b,  // (1)
    const float* __restrict__ bn_gamma, // (N)
    const float* __restrict__ bn_beta,  // (N)
    float* __restrict__ out_state,      // (B,N)
    float* __restrict__ out_bn)         // (B,N,D)
{
    int gid = blockIdx.x * blockDim.x + threadIdx.x;
    int n = gid >> 6;
    if (n >= NN) return;
    int lane = gid & 63;
    int d = lane & 31;
    int h = lane >> 5;

    float inv = 1.0f / fmaxf(cnt[n], 1.0f);
    float v0 = sums[(size_t)h       * NN * DD + (size_t)n * DD + d] * inv;
    float v1 = sums[(size_t)(h + 2) * NN * DD + (size_t)n * DD + d] * inv;

    // state: reduce v*state_w[d] over each half-wave (one batch per half)
    float sw = state_w[d];
    float s0 = v0 * sw, s1 = v1 * sw;
    #pragma unroll
    for (int m = 16; m >= 1; m >>= 1) {
        s0 += __shfl_xor(s0, m, 32);
        s1 += __shfl_xor(s1, m, 32);
    }
    if (d == 0) {
        float sb = state_b[0];
        out_state[(size_t)h       * NN + n] = s0 + sb;
        out_state[(size_t)(h + 2) * NN + n] = s1 + sb;
    }

    // mean/var over all B*D = 128 values
    float sum = v0 + v1;
    float sq  = v0 * v0 + v1 * v1;
    #pragma unroll
    for (int m = 32; m >= 1; m >>= 1) {
        sum += __shfl_xor(sum, m, 64);
        sq  += __shfl_xor(sq,  m, 64);
    }
    float mean  = sum * (1.0f / 128.0f);
    float var   = sq  * (1.0f / 128.0f) - mean * mean;
    float scale = rsqrtf(var + 1e-5f);
    float g = bn_gamma[n], be = bn_beta[n];

    out_bn[(size_t)h       * NN * DD + (size_t)n * DD + d] = (v0 - mean) * scale * g + be;
    out_bn[(size_t)(h + 2) * NN * DD + (size_t)n * DD + d] = (v1 - mean) * scale * g + be;
}

extern "C" void kernel_launch(void* const* d_in, const int* in_sizes, int n_in,
                              void* d_out, int out_size, void* d_ws, size_t ws_size,
                              hipStream_t stream) {
    const float* x        = (const float*)d_in[0];
    const int*   eidx     = (const int*)  d_in[1];
    const float* weight   = (const float*)d_in[2];
    const float* bias     = (const float*)d_in[3];
    const float* state_w  = (const float*)d_in[4];
    const float* state_b  = (const float*)d_in[5];
    const float* bn_gamma = (const float*)d_in[6];
    const float* bn_beta  = (const float*)d_in[7];

    float* sums = (float*)d_ws;                       // B*N*D
    float* cnt  = sums + (size_t)BB * NN * DD;        // N
    size_t zero_bytes = ((size_t)BB * NN * DD + NN) * sizeof(float);
    hipMemsetAsync(d_ws, 0, zero_bytes, stream);

    float* out_state = (float*)d_out;                 // B*N
    float* out_bn    = out_state + (size_t)BB * NN;   // B*N*D

    edge_kernel<<<EE / 4, 256, 0, stream>>>(x, eidx, weight, bias, sums, cnt);

    int node_threads = NN * 64;
    node_kernel<<<(node_threads + 255) / 256, 256, 0, stream>>>(
        sums, cnt, state_w, state_b, bn_gamma, bn_beta, out_state, out_bn);
}

// Round 3
// 210.721 us; speedup vs baseline: 1.1322x; 1.1322x over previous
//
#include <hip/hip_runtime.h>

#define BB 4
#define NN 10000
#define EE 200000
#define DD 32
#define ND ((size_t)NN * DD)

__device__ __forceinline__ float fast_tanh(float v) {
    float a = fabsf(v);
    float e = __expf(2.0f * a);            // e^{2|v|}; overflows to +inf for big a -> r = 1
    float r = 1.0f - 2.0f / (e + 1.0f);
    return copysignf(r, v);
}

// One wave (64 lanes) per edge.
// Load phase: lane l (q=l>>3, k=l&7) holds W[8t+q][4k..4k+3] for t=0..3 via 4 float4 loads
//   -> 4 VMEM instructions cover the whole 4KB weight tile, no lane duplication.
// Compute: acc[b][j] += x[b][8t+q] * W[8t+q][4k+j]  (x broadcast via 16 bpermutes)
// Reduce: xor-butterfly over lanes {8,16,32} -> every lane holds all 16 (b,j) totals
// Output: lane q owns (b=q>>1, cols 4k+2*(q&1)+{0,1}) -> 2 atomics/lane = 128 total.
__global__ __launch_bounds__(256) void edge_kernel(
    const float* __restrict__ x,        // (B,N,D)
    const int*   __restrict__ eidx,     // (2,E)
    const float* __restrict__ weight,   // (E,D,D)
    const float* __restrict__ bias,     // (E,D)
    float* __restrict__ sums,           // (B,N,D) accum
    float* __restrict__ cnt)            // (N)
{
    int wid = threadIdx.x >> 6;
    int e = blockIdx.x * 4 + wid;
    if (e >= EE) return;
    int lane = threadIdx.x & 63;
    int q = lane >> 3;   // 0..7
    int k = lane & 7;    // 0..7
    int c = k << 2;      // column base 0,4,...,28

    int src = eidx[e];
    int dst = eidx[EE + e];

    const float4* __restrict__ W4 = (const float4*)(weight + (size_t)e * (DD * DD));
    float4 w[4];
    w[0] = W4[lane];
    w[1] = W4[64 + lane];
    w[2] = W4[128 + lane];
    w[3] = W4[192 + lane];

    // xr[b] = x[b][src][lane&31] (lanes 32-63 mirror 0-31)
    size_t xoff = (size_t)src * DD + (lane & 31);
    float xr0 = x[xoff];
    float xr1 = x[xoff + ND];
    float xr2 = x[xoff + 2 * ND];
    float xr3 = x[xoff + 3 * ND];

    float acc[4][4] = {{0.f}};
#pragma unroll
    for (int t = 0; t < 4; ++t) {
        int rb = (t << 3) + q;             // row this lane's fragment belongs to
        float x0 = __shfl(xr0, rb, 64);
        float x1 = __shfl(xr1, rb, 64);
        float x2 = __shfl(xr2, rb, 64);
        float x3 = __shfl(xr3, rb, 64);
        acc[0][0] = fmaf(x0, w[t].x, acc[0][0]);
        acc[0][1] = fmaf(x0, w[t].y, acc[0][1]);
        acc[0][2] = fmaf(x0, w[t].z, acc[0][2]);
        acc[0][3] = fmaf(x0, w[t].w, acc[0][3]);
        acc[1][0] = fmaf(x1, w[t].x, acc[1][0]);
        acc[1][1] = fmaf(x1, w[t].y, acc[1][1]);
        acc[1][2] = fmaf(x1, w[t].z, acc[1][2]);
        acc[1][3] = fmaf(x1, w[t].w, acc[1][3]);
        acc[2][0] = fmaf(x2, w[t].x, acc[2][0]);
        acc[2][1] = fmaf(x2, w[t].y, acc[2][1]);
        acc[2][2] = fmaf(x2, w[t].z, acc[2][2]);
        acc[2][3] = fmaf(x2, w[t].w, acc[2][3]);
        acc[3][0] = fmaf(x3, w[t].x, acc[3][0]);
        acc[3][1] = fmaf(x3, w[t].y, acc[3][1]);
        acc[3][2] = fmaf(x3, w[t].z, acc[3][2]);
        acc[3][3] = fmaf(x3, w[t].w, acc[3][3]);
    }

    // butterfly reduce across lanes l^8, l^16, l^32 (static indices only)
#pragma unroll
    for (int b = 0; b < 4; ++b)
#pragma unroll
        for (int j = 0; j < 4; ++j) {
            float v = acc[b][j];
            v += __shfl_xor(v, 8, 64);
            v += __shfl_xor(v, 16, 64);
            v += __shfl_xor(v, 32, 64);
            acc[b][j] = v;
        }

    // lane owns (b = q>>1, cols c + 2*(q&1) + {0,1}); select with static indices
    bool pb0 = (q & 1) != 0, pb1 = (q & 2) != 0, pb2 = (q & 4) != 0;
    float e0_lo = pb1 ? (pb0 ? acc[1][2] : acc[1][0]) : (pb0 ? acc[0][2] : acc[0][0]);
    float e0_hi = pb1 ? (pb0 ? acc[3][2] : acc[3][0]) : (pb0 ? acc[2][2] : acc[2][0]);
    float e1_lo = pb1 ? (pb0 ? acc[1][3] : acc[1][1]) : (pb0 ? acc[0][3] : acc[0][1]);
    float e1_hi = pb1 ? (pb0 ? acc[3][3] : acc[3][1]) : (pb0 ? acc[2][3] : acc[2][1]);
    float a0 = pb2 ? e0_hi : e0_lo;
    float a1 = pb2 ? e1_hi : e1_lo;

    int b   = q >> 1;
    int col = c + ((q & 1) << 1);
    float2 bv = *(const float2*)&bias[(size_t)e * DD + col];
    float o0 = fast_tanh(a0 + bv.x);
    float o1 = fast_tanh(a1 + bv.y);

    float* p = &sums[(size_t)b * ND + (size_t)dst * DD + col];
    atomicAdd(p,     o0);
    atomicAdd(p + 1, o1);
    if (lane == 0) atomicAdd(&cnt[dst], 1.0f);
}

// One wave per node: agg = sums/max(cnt,1); state; batch-norm over (B,D)=128 vals.
__global__ __launch_bounds__(256) void node_kernel(
    const float* __restrict__ sums,     // (B,N,D)
    const float* __restrict__ cnt,      // (N)
    const float* __restrict__ state_w,  // (D,1)
    const float* __restrict__ state_b,  // (1)
    const float* __restrict__ bn_gamma, // (N)
    const float* __restrict__ bn_beta,  // (N)
    float* __restrict__ out_state,      // (B,N)
    float* __restrict__ out_bn)         // (B,N,D)
{
    int gid = blockIdx.x * blockDim.x + threadIdx.x;
    int n = gid >> 6;
    if (n >= NN) return;
    int lane = gid & 63;
    int d = lane & 31;
    int h = lane >> 5;

    float inv = 1.0f / fmaxf(cnt[n], 1.0f);
    float v0 = sums[(size_t)h * ND + (size_t)n * DD + d] * inv;
    float v1 = sums[(size_t)(h + 2) * ND + (size_t)n * DD + d] * inv;

    // state: reduce v*state_w[d] over each half-wave (one batch per half)
    float sw = state_w[d];
    float s0 = v0 * sw, s1 = v1 * sw;
#pragma unroll
    for (int m = 16; m >= 1; m >>= 1) {
        s0 += __shfl_xor(s0, m, 32);
        s1 += __shfl_xor(s1, m, 32);
    }
    if (d == 0) {
        float sb = state_b[0];
        out_state[(size_t)h * NN + n]       = s0 + sb;
        out_state[(size_t)(h + 2) * NN + n] = s1 + sb;
    }

    // mean/var over all B*D = 128 values
    float sum = v0 + v1;
    float sq  = v0 * v0 + v1 * v1;
#pragma unroll
    for (int m = 32; m >= 1; m >>= 1) {
        sum += __shfl_xor(sum, m, 64);
        sq  += __shfl_xor(sq,  m, 64);
    }
    float mean  = sum * (1.0f / 128.0f);
    float var   = sq  * (1.0f / 128.0f) - mean * mean;
    float scale = rsqrtf(var + 1e-5f);
    float g = bn_gamma[n], be = bn_beta[n];

    out_bn[(size_t)h * ND + (size_t)n * DD + d]       = (v0 - mean) * scale * g + be;
    out_bn[(size_t)(h + 2) * ND + (size_t)n * DD + d] = (v1 - mean) * scale * g + be;
}

extern "C" void kernel_launch(void* const* d_in, const int* in_sizes, int n_in,
                              void* d_out, int out_size, void* d_ws, size_t ws_size,
                              hipStream_t stream) {
    const float* x        = (const float*)d_in[0];
    const int*   eidx     = (const int*)  d_in[1];
    const float* weight   = (const float*)d_in[2];
    const float* bias     = (const float*)d_in[3];
    const float* state_w  = (const float*)d_in[4];
    const float* state_b  = (const float*)d_in[5];
    const float* bn_gamma = (const float*)d_in[6];
    const float* bn_beta  = (const float*)d_in[7];

    float* sums = (float*)d_ws;                       // B*N*D
    float* cnt  = sums + (size_t)BB * ND / BB * BB;   // == sums + B*N*D
    cnt = sums + (size_t)BB * NN * DD;
    size_t zero_bytes = ((size_t)BB * NN * DD + NN) * sizeof(float);
    hipMemsetAsync(d_ws, 0, zero_bytes, stream);

    float* out_state = (float*)d_out;                 // B*N
    float* out_bn    = out_state + (size_t)BB * NN;   // B*N*D

    edge_kernel<<<EE / 4, 256, 0, stream>>>(x, eidx, weight, bias, sums, cnt);

    int node_threads = NN * 64;
    node_kernel<<<(node_threads + 255) / 256, 256, 0, stream>>>(
        sums, cnt, state_w, state_b, bn_gamma, bn_beta, out_state, out_bn);
}

// Round 4
// 175.931 us; speedup vs baseline: 1.3561x; 1.1977x over previous
//
#include <hip/hip_runtime.h>

#define BB 4
#define NN 10000
#define EE 200000
#define DD 32
#define ND ((size_t)NN * DD)

__device__ __forceinline__ float fast_tanh(float v) {
    float a = fabsf(v);
    float e = __expf(2.0f * a);            // e^{2|v|}; overflows to +inf for big a -> r = 1
    float r = 1.0f - 2.0f / (e + 1.0f);
    return copysignf(r, v);
}

__device__ __forceinline__ float bcast(float v, int lane) {
    return __int_as_float(__builtin_amdgcn_readlane(__float_as_int(v), lane));
}

// One wave (64 lanes) per edge. ZERO DS (shuffle) ops.
// lane l: d = l&31. xr[b] vector-loaded (lane i holds x[b][src][i], i<32).
// Inner loop: x broadcast via v_readlane -> SGPR operand of v_fma (VALU pipe only).
// Every lane accumulates all 4 batches; half-waves write disjoint batches.
__global__ __launch_bounds__(256) void edge_kernel(
    const float* __restrict__ x,        // (B,N,D)
    const int*   __restrict__ eidx,     // (2,E)
    const float* __restrict__ weight,   // (E,D,D)
    const float* __restrict__ bias,     // (E,D)
    float* __restrict__ sums,           // (B,N,D) accum
    float* __restrict__ cnt)            // (N)
{
    int wid = __builtin_amdgcn_readfirstlane((int)(threadIdx.x >> 6));
    int e = blockIdx.x * 4 + wid;
    if (e >= EE) return;
    int lane = threadIdx.x & 63;
    int d = lane & 31;
    bool hi = lane >= 32;

    int src = __builtin_amdgcn_readfirstlane(eidx[e]);
    int dst = __builtin_amdgcn_readfirstlane(eidx[EE + e]);

    // lane i (i = lane&31) holds x[b][src][i]; lanes 32-63 duplicate (harmless)
    size_t xoff = (size_t)src * DD + d;
    float xr0 = x[xoff];
    float xr1 = x[xoff + ND];
    float xr2 = x[xoff + 2 * ND];
    float xr3 = x[xoff + 3 * ND];

    const float* __restrict__ W = weight + (size_t)e * (DD * DD);
    float acc0 = 0.f, acc1 = 0.f, acc2 = 0.f, acc3 = 0.f;
#pragma unroll
    for (int i = 0; i < DD; ++i) {
        float w  = W[i * DD + d];          // R1's proven pattern: 32 consecutive floats/row
        float x0 = bcast(xr0, i);          // v_readlane -> SGPR (no DS pipe)
        float x1 = bcast(xr1, i);
        float x2 = bcast(xr2, i);
        float x3 = bcast(xr3, i);
        acc0 = fmaf(x0, w, acc0);          // 1 SGPR + 2 VGPR operands: legal VOP3
        acc1 = fmaf(x1, w, acc1);
        acc2 = fmaf(x2, w, acc2);
        acc3 = fmaf(x3, w, acc3);
    }
    float bv = bias[(size_t)e * DD + d];
    // lanes 0-31 own batches {0,1}; lanes 32-63 own batches {2,3}
    float a0 = hi ? acc2 : acc0;
    float a1 = hi ? acc3 : acc1;
    float o0 = fast_tanh(a0 + bv);
    float o1 = fast_tanh(a1 + bv);

    size_t base = (size_t)dst * DD + d;
    float* p = &sums[(hi ? 2 * ND : 0) + base];
    atomicAdd(p, o0);           // batch 0 or 2
    atomicAdd(p + ND, o1);      // batch 1 or 3
    if (lane == 0) atomicAdd(&cnt[dst], 1.0f);
}

// One wave per node: agg = sums/max(cnt,1); state; batch-norm over (B,D)=128 vals.
__global__ __launch_bounds__(256) void node_kernel(
    const float* __restrict__ sums,     // (B,N,D)
    const float* __restrict__ cnt,      // (N)
    const float* __restrict__ state_w,  // (D,1)
    const float* __restrict__ state_b,  // (1)
    const float* __restrict__ bn_gamma, // (N)
    const float* __restrict__ bn_beta,  // (N)
    float* __restrict__ out_state,      // (B,N)
    float* __restrict__ out_bn)         // (B,N,D)
{
    int gid = blockIdx.x * blockDim.x + threadIdx.x;
    int n = gid >> 6;
    if (n >= NN) return;
    int lane = gid & 63;
    int d = lane & 31;
    int h = lane >> 5;

    float inv = 1.0f / fmaxf(cnt[n], 1.0f);
    float v0 = sums[(size_t)h * ND + (size_t)n * DD + d] * inv;
    float v1 = sums[(size_t)(h + 2) * ND + (size_t)n * DD + d] * inv;

    // state: reduce v*state_w[d] over each half-wave (one batch per half)
    float sw = state_w[d];
    float s0 = v0 * sw, s1 = v1 * sw;
#pragma unroll
    for (int m = 16; m >= 1; m >>= 1) {
        s0 += __shfl_xor(s0, m, 32);
        s1 += __shfl_xor(s1, m, 32);
    }
    if (d == 0) {
        float sb = state_b[0];
        out_state[(size_t)h * NN + n]       = s0 + sb;
        out_state[(size_t)(h + 2) * NN + n] = s1 + sb;
    }

    // mean/var over all B*D = 128 values
    float sum = v0 + v1;
    float sq  = v0 * v0 + v1 * v1;
#pragma unroll
    for (int m = 32; m >= 1; m >>= 1) {
        sum += __shfl_xor(sum, m, 64);
        sq  += __shfl_xor(sq,  m, 64);
    }
    float mean  = sum * (1.0f / 128.0f);
    float var   = sq  * (1.0f / 128.0f) - mean * mean;
    float scale = rsqrtf(var + 1e-5f);
    float g = bn_gamma[n], be = bn_beta[n];

    out_bn[(size_t)h * ND + (size_t)n * DD + d]       = (v0 - mean) * scale * g + be;
    out_bn[(size_t)(h + 2) * ND + (size_t)n * DD + d] = (v1 - mean) * scale * g + be;
}

extern "C" void kernel_launch(void* const* d_in, const int* in_sizes, int n_in,
                              void* d_out, int out_size, void* d_ws, size_t ws_size,
                              hipStream_t stream) {
    const float* x        = (const float*)d_in[0];
    const int*   eidx     = (const int*)  d_in[1];
    const float* weight   = (const float*)d_in[2];
    const float* bias     = (const float*)d_in[3];
    const float* state_w  = (const float*)d_in[4];
    const float* state_b  = (const float*)d_in[5];
    const float* bn_gamma = (const float*)d_in[6];
    const float* bn_beta  = (const float*)d_in[7];

    float* sums = (float*)d_ws;                       // B*N*D
    float* cnt  = sums + (size_t)BB * NN * DD;        // N
    size_t zero_bytes = ((size_t)BB * NN * DD + NN) * sizeof(float);
    hipMemsetAsync(d_ws, 0, zero_bytes, stream);

    float* out_state = (float*)d_out;                 // B*N
    float* out_bn    = out_state + (size_t)BB * NN;   // B*N*D

    edge_kernel<<<EE / 4, 256, 0, stream>>>(x, eidx, weight, bias, sums, cnt);

    int node_threads = NN * 64;
    node_kernel<<<(node_threads + 255) / 256, 256, 0, stream>>>(
        sums, cnt, state_w, state_b, bn_gamma, bn_beta, out_state, out_bn);
}